// Round 11
// baseline (185.296 us; speedup 1.0000x reference)
//
#include <hip/hip_runtime.h>
#include <hip/hip_bf16.h>

#define TPB 512
#define TPB_PREP 256
#define PREP_BLOCKS 64

typedef __attribute__((ext_vector_type(8))) short short8;
typedef __attribute__((ext_vector_type(4))) float f32x4;

// ---- weight image byte offsets (d_ws; whole image mirrored in LDS) ----
// MFMA A-frag HW slot map (16x16x32): lane(q,n16) holds A[n16][k] for
//   k = 16*(j>>2) + 4*q + (j&3),  j=0..7.
// General layers use phys_k(s,q,j) = 16*(2*s + (j>>2)) + 4*q + (j&3) so the
// producer C-layout (row = 4q+r) matches the consumer B-frag register-local.
// L1 uses the 4-quad j0 distribution: k=4q slots carry {a0,a1,a2,ce}.
// Decoder D1F per-quad feature map: q0 j0..7 -> icO[0..7]; q1 j0..3 ->
// icO[8..11]; q2 j0..3 -> z[0..3]; q3 j0..3 -> z[4..7]; rest zero-padded,
// so each quad supplies exactly the z values it computes (no exchange).
#define G_W2F   0        // [t=3][s=4][lane=64][j=8] bf16  12288  (A-frags, perm)
#define G_MVF   12288    // [s=4][64][8] bf16               4096  (A-frags, perm)
#define G_D1F   16384    // [t=2][64][8] bf16               2048  (A-frags, per-quad map)
#define G_D2F   18432    // [64][8] bf16                    1024  (A-frags, perm)
#define G_CEAB  19456    // [e=4][lane=64][mt=8] ushort     4096  (L1 j0-coeffs, b128/lane)
#define G_B2P   23552    // [48] f32 (pad 0)
#define G_B3    23744    // [128] f32
#define G_BMV   24256    // [16] f32 (bm|bv)
#define G_D1C   24320    // [32] f32 (Wd1 col0 + bd1)
#define G_BD2   24448    // [16] f32 (pad 0)
#define G_W3F   24512    // [nt=8][s=2][64][8] bf16        16384  (A-frags, perm)
#define G_END   40896    // LDS alloc 40960 = exactly 160KiB/4 -> 4 blocks/CU

__device__ __forceinline__ unsigned short f2bf(float f) {
    unsigned int u = __float_as_uint(f);
    unsigned int r = u + 0x7fffu + ((u >> 16) & 1u);   // RNE
    return (unsigned short)(r >> 16);
}
__device__ __forceinline__ unsigned int pk(float a, float b) {
    __hip_bfloat162 h = __float22bfloat162_rn(make_float2(a, b));
    unsigned int u; __builtin_memcpy(&u, &h, 4); return u;
}
__device__ __forceinline__ unsigned short bfbits(float v) {
    return (unsigned short)(pk(v, v) & 0xffffu);
}

__global__ void prep_kernel(
    const float* __restrict__ W1, const float* __restrict__ b1,
    const float* __restrict__ W2, const float* __restrict__ b2,
    const float* __restrict__ W3, const float* __restrict__ b3,
    const float* __restrict__ Wm, const float* __restrict__ bm,
    const float* __restrict__ Wv, const float* __restrict__ bv,
    const float* __restrict__ Wd1, const float* __restrict__ bd1,
    const float* __restrict__ Wd2, const float* __restrict__ bd2,
    unsigned char* __restrict__ ws)
{
    const int g0 = blockIdx.x * TPB_PREP + threadIdx.x;
    const int gs = gridDim.x * TPB_PREP;
    // W2 as A-fragments of s^T = W2 . x1^T, permuted K
    unsigned short* w2f = (unsigned short*)(ws + G_W2F);
    for (int i = g0; i < 6144; i += gs) {
        int j = i & 7, lane = (i >> 3) & 63, ts = i >> 9;
        int t = ts >> 2, s = ts & 3, q = lane >> 4;
        int n = 16 * t + (lane & 15);
        int phys = 16 * (2 * s + (j >> 2)) + 4 * q + (j & 3);   // 0..127
        w2f[i] = (n < 39) ? f2bf(W2[n * 128 + phys]) : 0;
    }
    // W3 as A-fragments of x3^T = W3 . s^T, permuted K (39 padded to 64)
    unsigned short* w3f = (unsigned short*)(ws + G_W3F);
    for (int i = g0; i < 8192; i += gs) {
        int j = i & 7, lane = (i >> 3) & 63, ns = i >> 9;
        int nt = ns >> 1, s = ns & 1, q = lane >> 4;
        int n = 16 * nt + (lane & 15);
        int phys = 16 * (2 * s + (j >> 2)) + 4 * q + (j & 3);   // 0..63
        w3f[i] = (phys < 39) ? f2bf(W3[n * 39 + phys]) : 0;
    }
    // Wm|Wv as A-fragments, permuted K=128
    unsigned short* mvf = (unsigned short*)(ws + G_MVF);
    for (int i = g0; i < 2048; i += gs) {
        int j = i & 7, lane = (i >> 3) & 63, s = i >> 9;
        int q = lane >> 4, n = lane & 15;
        int phys = 16 * (2 * s + (j >> 2)) + 4 * q + (j & 3);
        mvf[i] = f2bf(n < 8 ? Wm[n * 128 + phys] : Wv[(n - 8) * 128 + phys]);
    }
    // Wd1 as A-fragments, per-quad feature map (see header comment)
    unsigned short* d1f = (unsigned short*)(ws + G_D1F);
    for (int i = g0; i < 1024; i += gs) {
        int j = i & 7, lane = (i >> 3) & 63, tt = i >> 9;
        int q = lane >> 4, n = 16 * tt + (lane & 15);
        float v = 0.f;
        if (q == 0)      v = Wd1[n * 25 + 5 + j];            // icO[0..7]
        else if (j < 4)  v = Wd1[n * 25 + 13 + 4 * (q - 1) + j];
        // q1 j0..3 -> cols 13..16 (icO[8..11]); q2 -> 17..20 (z0..3);
        // q3 -> 21..24 (z4..7); all j>=4 (q>0) zero.
        d1f[i] = (q == 0 || j < 4) ? f2bf(v) : 0;
    }
    // Wd2 as A-fragments, permuted K=32
    unsigned short* d2f = (unsigned short*)(ws + G_D2F);
    for (int i = g0; i < 512; i += gs) {
        int j = i & 7, lane = i >> 3;
        int q = lane >> 4, n = lane & 15;
        int phys = 16 * (j >> 2) + 4 * q + (j & 3);
        d2f[i] = (n < 12) ? f2bf(Wd2[n * 32 + phys]) : 0;
    }
    // L1 coefficient image: [e][lane][mt] ushort (one ds_read_b128 per lane):
    //   quad q j0 slot carries: q0 -> a0 = W1[n][10], q1 -> a1 = W1[n][11],
    //   q2 -> a2 = W1[n][12], q3 -> ce = W1[n][0] + W1[n][6+e] + b1[n],
    //   with n = 16*mt + n16.
    unsigned short* ceab = (unsigned short*)(ws + G_CEAB);
    for (int i = g0; i < 2048; i += gs) {
        int mt = i & 7, lane = (i >> 3) & 63, e = i >> 9;
        int q = lane >> 4, n = 16 * mt + (lane & 15);
        float v = (q == 0) ? W1[n * 13 + 10]
                : (q == 1) ? W1[n * 13 + 11]
                : (q == 2) ? W1[n * 13 + 12]
                           : (W1[n * 13 + 0] + W1[n * 13 + 6 + e] + b1[n]);
        ceab[i] = f2bf(v);
    }
    float* fb = (float*)(ws + G_B2P);
    for (int i = g0; i < 48; i += gs) fb[i] = (i < 39) ? b2[i] : 0.f;
    fb = (float*)(ws + G_B3);
    for (int i = g0; i < 128; i += gs) fb[i] = b3[i];
    fb = (float*)(ws + G_BMV);
    for (int i = g0; i < 16; i += gs) fb[i] = (i < 8) ? bm[i] : bv[i - 8];
    fb = (float*)(ws + G_D1C);
    for (int i = g0; i < 32; i += gs) fb[i] = Wd1[i * 25 + 0] + bd1[i];
    fb = (float*)(ws + G_BD2);
    for (int i = g0; i < 16; i += gs) fb[i] = (i < 12) ? bd2[i] : 0.f;
}

union S8 { short8 v; uint4 u; };

#define MFMA(a, b, c) __builtin_amdgcn_mfma_f32_16x16x32_bf16(a, b, c, 0, 0, 0)

// r10 base (60us) + two changes:
// 1) CEAB relayout [e][lane][mt]: L1 coeffs fetched with 1 ds_read_b128 per
//    edge (was 8 ds_read_u16), coeff extracted per mt with 1 VALU op.
// 2) TPB=512 (8 waves/block): the 40960B LDS image now serves 8 waves ->
//    residency cap rises 16 -> 28 waves/CU (VGPR=68-bound), staging per
//    wave halves, block count halves (ramp/tail shrinks). No VGPR-cap
//    pressure (launch_bounds(512,2) -> 256-reg cap; spill tripwire:
//    WRITE_SIZE >> 37 MB).
__global__ __launch_bounds__(TPB, 2) void vae_mfma(
    const float* __restrict__ ic, const float* __restrict__ cc,
    const float* __restrict__ eps,
    const unsigned char* __restrict__ ws,
    float* __restrict__ out, int B)
{
    __shared__ __attribute__((aligned(16))) unsigned char lds[G_END];
    const int tid = threadIdx.x;

    {   // weight image -> LDS (linear, coalesced; L2-hot)
        const uint4* src = (const uint4*)ws;
        uint4* dst = (uint4*)lds;
        #pragma unroll
        for (int it = 0; it < 5; it++) {
            int idx = it * TPB + tid;
            if (idx < G_END / 16) dst[idx] = src[idx];
        }
    }
    __syncthreads();

    const int lane = tid & 63, w = tid >> 6;          // w = 0..7
    const int quad = lane >> 4, n16 = lane & 15;
    const long rb = ((long)blockIdx.x * 8 + w) * 16;
    const long Rl = rb + n16;              // this lane's batch row

    // ---- per-quad predicate values (k=4q slot), packed bf16 low-half ----
    unsigned int bpv[4];
    {
        const float* crow = cc + Rl * 30;
        float pv0, pv1, pv2, pv3;
        if (quad == 0) {                    // pa: cols 0..3
            float2 t0 = *(const float2*)(crow);
            float2 t1 = *(const float2*)(crow + 2);
            pv0 = t0.x; pv1 = t0.y; pv2 = t1.x; pv3 = t1.y;
        } else if (quad == 1) {             // pb: cols 10..13
            float2 t0 = *(const float2*)(crow + 10);
            float2 t1 = *(const float2*)(crow + 12);
            pv0 = t0.x; pv1 = t0.y; pv2 = t1.x; pv3 = t1.y;
        } else if (quad == 2) {             // pc: cols 14,18,22,26
            pv0 = crow[14]; pv1 = crow[18]; pv2 = crow[22]; pv3 = crow[26];
        } else {                            // bias lane: 1.0
            pv0 = pv1 = pv2 = pv3 = 1.0f;
        }
        bpv[0] = (unsigned int)bfbits(pv0);
        bpv[1] = (unsigned int)bfbits(pv1);
        bpv[2] = (unsigned int)bfbits(pv2);
        bpv[3] = (unsigned int)bfbits(pv3);
    }

    // ---- W2 A-frags resident (from LDS) + per-quad bias vectors ----
    S8 W2F[12];
    #pragma unroll
    for (int ts = 0; ts < 12; ts++)
        W2F[ts].u = *(const uint4*)(lds + G_W2F + (ts * 64 + lane) * 16);
    const float* b2p = (const float*)(lds + G_B2P);
    f32x4 b2q[3];
    #pragma unroll
    for (int t = 0; t < 3; t++)
        b2q[t] = *(const f32x4*)(b2p + 16 * t + 4 * quad);

    f32x4 ss0 = {0,0,0,0}, ss1 = {0,0,0,0}, ss2 = {0,0,0,0};

    // ---- message MLP: L1 (x1^T tiles) -> in-reg pack -> L2 (s^T) ----
    #pragma unroll
    for (int e = 0; e < 4; e++) {
        S8 bp;                              // B: k=4q slot = this quad's p-value
        bp.u.x = bpv[e]; bp.u.y = 0u; bp.u.z = 0u; bp.u.w = 0u;
        S8 ce8;                             // this lane's 8 mt-coeffs, 1 b128
        ce8.u = *(const uint4*)(lds + G_CEAB + e * 1024 + lane * 16);
        S8 xf[4];                           // x1^T B-frags for L2 (perm K)
        #pragma unroll
        for (int mt = 0; mt < 8; mt++) {
            unsigned int cws[4] = {ce8.u.x, ce8.u.y, ce8.u.z, ce8.u.w};
            unsigned int cw = cws[mt >> 1];           // compile-time index
            S8 af;                          // A: k=4q slot = coeff type q
            af.u.x = (mt & 1) ? (cw >> 16) : (cw & 0xffffu);
            af.u.y = 0u; af.u.z = 0u; af.u.w = 0u;
            f32x4 z4 = {0,0,0,0};
            f32x4 cr = MFMA(af.v, bp.v, z4);   // lane: x1[b=n16][16mt+4q+r]
            unsigned int lo = pk(fmaxf(cr[0], 0.f), fmaxf(cr[1], 0.f));
            unsigned int hi = pk(fmaxf(cr[2], 0.f), fmaxf(cr[3], 0.f));
            if ((mt & 1) == 0) { xf[mt >> 1].u.x = lo; xf[mt >> 1].u.y = hi; }
            else               { xf[mt >> 1].u.z = lo; xf[mt >> 1].u.w = hi; }
        }
        f32x4 c0 = b2q[0], c1 = b2q[1], c2 = b2q[2];
        #pragma unroll
        for (int s = 0; s < 4; s++) {
            c0 = MFMA(W2F[s].v,     xf[s].v, c0);
            c1 = MFMA(W2F[4 + s].v, xf[s].v, c1);
            c2 = MFMA(W2F[8 + s].v, xf[s].v, c2);
        }
        #pragma unroll
        for (int r = 0; r < 4; r++) {
            ss0[r] += fmaxf(c0[r], 0.f);
            ss1[r] += fmaxf(c1[r], 0.f);
            ss2[r] += fmaxf(c2[r], 0.f);
        }
    }

    // ---- s^T B-frags (K=64, tiles 3 valid + 1 zero pad) ----
    S8 sf0, sf1;
    sf0.u.x = pk(ss0[0], ss0[1]); sf0.u.y = pk(ss0[2], ss0[3]);
    sf0.u.z = pk(ss1[0], ss1[1]); sf0.u.w = pk(ss1[2], ss1[3]);
    sf1.u.x = pk(ss2[0], ss2[1]); sf1.u.y = pk(ss2[2], ss2[3]);
    sf1.u.z = 0u; sf1.u.w = 0u;   // rows 48..63 pad (rows 39..47 exact zero)

    // ---- L3: x3^T = W3 . s^T ; pack heads B-frags on the fly ----
    const uint4* w3l = (const uint4*)(lds + G_W3F);
    const float* b3p = (const float*)(lds + G_B3);
    S8 hf[4];
    #pragma unroll
    for (int nt = 0; nt < 8; nt++) {
        f32x4 c = *(const f32x4*)(b3p + nt * 16 + 4 * quad);
        S8 a0, a1;
        a0.u = w3l[(nt * 2 + 0) * 64 + lane];
        a1.u = w3l[(nt * 2 + 1) * 64 + lane];
        c = MFMA(a0.v, sf0.v, c);
        c = MFMA(a1.v, sf1.v, c);
        unsigned int lo = pk(fmaxf(c[0], 0.f), fmaxf(c[1], 0.f));
        unsigned int hi = pk(fmaxf(c[2], 0.f), fmaxf(c[3], 0.f));
        if ((nt & 1) == 0) { hf[nt >> 1].u.x = lo; hf[nt >> 1].u.y = hi; }
        else               { hf[nt >> 1].u.z = lo; hf[nt >> 1].u.w = hi; }
    }

    // ---- heads: cm = [mn|lv]^T rows 4q+r; cm2 = same weights half-rotated
    //      (rows (4q+r+8)&15) so each lane owns its (mn,lv) pair ----
    f32x4 cm  = *(const f32x4*)((const float*)(lds + G_BMV) + 4 * quad);
    f32x4 cm2 = *(const f32x4*)((const float*)(lds + G_BMV) + 4 * ((quad + 2) & 3));
    const int laneSw = quad * 16 + ((n16 + 8) & 15);
    #pragma unroll
    for (int s = 0; s < 4; s++) {
        S8 a, a2;
        a.u  = *(const uint4*)(lds + G_MVF + (s * 64 + lane) * 16);
        a2.u = *(const uint4*)(lds + G_MVF + (s * 64 + laneSw) * 16);
        cm  = MFMA(a.v,  hf[s].v, cm);
        cm2 = MFMA(a2.v, hf[s].v, cm2);
    }

    // ---- reparameterization, fully lane-local ----
    float4 ev = *(const float4*)(eps + Rl * 8 + 4 * (quad & 1));
    f32x4 zz;
    {
        const bool lo2 = (quad < 2);
        float mn0 = lo2 ? cm[0] : cm2[0], lv0 = lo2 ? cm2[0] : cm[0];
        float mn1 = lo2 ? cm[1] : cm2[1], lv1 = lo2 ? cm2[1] : cm[1];
        float mn2 = lo2 ? cm[2] : cm2[2], lv2 = lo2 ? cm2[2] : cm[2];
        float mn3 = lo2 ? cm[3] : cm2[3], lv3 = lo2 ? cm2[3] : cm[3];
        zz[0] = fmaf(ev.x, __expf(0.5f * lv0), mn0);
        zz[1] = fmaf(ev.y, __expf(0.5f * lv1), mn1);
        zz[2] = fmaf(ev.z, __expf(0.5f * lv2), mn2);
        zz[3] = fmaf(ev.w, __expf(0.5f * lv3), mn3);
    }
    // stores: q0/q1 -> means (cm = mn rows), q2/q3 -> logvar (cm = lv rows)
    float* pml = (float*)((quad < 2) ? (out + (long)B * 12) : (out + (long)B * 20));
    *(float4*)(pml + Rl * 8 + 4 * (quad & 1)) = *(float4*)&cm;
    if (quad < 2)
        *(float4*)(out + (long)B * 28 + Rl * 8 + 4 * quad) = *(float4*)&zz;

    // ---- decoder input B-frag, per-quad feature map (no exchange) ----
    S8 df;
    if (quad == 0) {                        // icO[0..7] = ic cols 0..3,10..13
        const float* irow = ic + Rl * 30;
        float2 a0 = *(const float2*)(irow);
        float2 a1 = *(const float2*)(irow + 2);
        float2 a2 = *(const float2*)(irow + 10);
        float2 a3 = *(const float2*)(irow + 12);
        df.u.x = pk(a0.x, a0.y); df.u.y = pk(a1.x, a1.y);
        df.u.z = pk(a2.x, a2.y); df.u.w = pk(a3.x, a3.y);
    } else if (quad == 1) {                 // icO[8..11] = ic cols 14,18,22,26
        const float* irow = ic + Rl * 30;
        df.u.x = pk(irow[14], irow[18]);
        df.u.y = pk(irow[22], irow[26]);
        df.u.z = 0u; df.u.w = 0u;
    } else {                                // q2: z[0..3], q3: z[4..7] (local)
        df.u.x = pk(zz[0], zz[1]);
        df.u.y = pk(zz[2], zz[3]);
        df.u.z = 0u; df.u.w = 0u;
    }

    // ---- decoder layer 1: h^T (2 tiles) ----
    const float* d1c = (const float*)(lds + G_D1C);
    S8 a;
    f32x4 ct = *(const f32x4*)(d1c + 4 * quad);
    a.u = *(const uint4*)(lds + G_D1F + (0 * 64 + lane) * 16);
    f32x4 h0 = MFMA(a.v, df.v, ct);
    ct = *(const f32x4*)(d1c + 16 + 4 * quad);
    a.u = *(const uint4*)(lds + G_D1F + (1 * 64 + lane) * 16);
    f32x4 h1 = MFMA(a.v, df.v, ct);
    S8 hf2;
    hf2.u.x = pk(fmaxf(h0[0], 0.f), fmaxf(h0[1], 0.f));
    hf2.u.y = pk(fmaxf(h0[2], 0.f), fmaxf(h0[3], 0.f));
    hf2.u.z = pk(fmaxf(h1[0], 0.f), fmaxf(h1[1], 0.f));
    hf2.u.w = pk(fmaxf(h1[2], 0.f), fmaxf(h1[3], 0.f));

    // ---- decoder layer 2 + sigmoid + coalesced float4 recon store ----
    f32x4 c2 = *(const f32x4*)((const float*)(lds + G_BD2) + 4 * quad);
    S8 a2; a2.u = *(const uint4*)(lds + G_D2F + lane * 16);
    c2 = MFMA(a2.v, hf2.v, c2);
    if (quad < 3) {
        float4 o;
        o.x = 1.f / (1.f + __expf(-c2[0]));
        o.y = 1.f / (1.f + __expf(-c2[1]));
        o.z = 1.f / (1.f + __expf(-c2[2]));
        o.w = 1.f / (1.f + __expf(-c2[3]));
        *(float4*)(out + Rl * 12 + 4 * quad) = o;
    }
}

extern "C" void kernel_launch(void* const* d_in, const int* in_sizes, int n_in,
                              void* d_out, int out_size, void* d_ws, size_t ws_size,
                              hipStream_t stream) {
    const float* ic  = (const float*)d_in[0];   // initial_c [B,30]
    const float* cc  = (const float*)d_in[2];   // current_c [B,30]
    const float* eps = (const float*)d_in[3];   // eps [B,8]

    const int B = in_sizes[3] / 8;              // 262144
    const int nblocks = B / 128;                // 2048 (8 waves x 16 rows)

    prep_kernel<<<PREP_BLOCKS, TPB_PREP, 0, stream>>>(
        (const float*)d_in[4],  (const float*)d_in[5],
        (const float*)d_in[6],  (const float*)d_in[7],
        (const float*)d_in[8],  (const float*)d_in[9],
        (const float*)d_in[10], (const float*)d_in[11],
        (const float*)d_in[12], (const float*)d_in[13],
        (const float*)d_in[14], (const float*)d_in[15],
        (const float*)d_in[16], (const float*)d_in[17],
        (unsigned char*)d_ws);
    vae_mfma<<<nblocks, TPB, 0, stream>>>(
        ic, cc, eps, (const unsigned char*)d_ws, (float*)d_out, B);
}

// Round 12
// 177.921 us; speedup vs baseline: 1.0415x; 1.0415x over previous
//
#include <hip/hip_runtime.h>
#include <hip/hip_bf16.h>

#define TPB 256
#define PREP_BLOCKS 64

typedef __attribute__((ext_vector_type(8))) short short8;
typedef __attribute__((ext_vector_type(4))) float f32x4;

// ---- weight image byte offsets (d_ws; whole image mirrored in LDS) ----
// MFMA A-frag HW slot map (16x16x32): lane(q,n16) holds A[n16][k] for
//   k = 16*(j>>2) + 4*q + (j&3),  j=0..7.
// General layers use phys_k(s,q,j) = 16*(2*s + (j>>2)) + 4*q + (j&3) so the
// producer C-layout (row = 4q+r) matches the consumer B-frag register-local.
// L1 uses the 4-quad j0 distribution: k=4q slots carry {a0,a1,a2,ce}.
// Decoder D1F per-quad feature map: q0 j0..7 -> icO[0..7]; q1 j0..3 ->
// icO[8..11]; q2 j0..3 -> z[0..3]; q3 j0..3 -> z[4..7]; rest zero-padded,
// so each quad supplies exactly the z values it computes (no exchange).
#define G_W2F   0        // [t=3][s=4][lane=64][j=8] bf16  12288  (A-frags, perm)
#define G_MVF   12288    // [s=4][64][8] bf16               4096  (A-frags, perm)
#define G_D1F   16384    // [t=2][64][8] bf16               2048  (A-frags, per-quad map)
#define G_D2F   18432    // [64][8] bf16                    1024  (A-frags, perm)
#define G_CEAB  19456    // [e=4][lane=64][mt=8] ushort     4096  (L1 j0-coeffs, b128/lane)
#define G_B2P   23552    // [48] f32 (pad 0)
#define G_B3    23744    // [128] f32
#define G_BMV   24256    // [16] f32 (bm|bv)
#define G_D1C   24320    // [32] f32 (Wd1 col0 + bd1)
#define G_BD2   24448    // [16] f32 (pad 0)
#define G_W3F   24512    // [nt=8][s=2][64][8] bf16        16384  (A-frags, perm)
#define G_END   40896    // LDS alloc 40960 = exactly 160KiB/4 -> 4 blocks/CU

__device__ __forceinline__ unsigned short f2bf(float f) {
    unsigned int u = __float_as_uint(f);
    unsigned int r = u + 0x7fffu + ((u >> 16) & 1u);   // RNE
    return (unsigned short)(r >> 16);
}
__device__ __forceinline__ unsigned int pk(float a, float b) {
    __hip_bfloat162 h = __float22bfloat162_rn(make_float2(a, b));
    unsigned int u; __builtin_memcpy(&u, &h, 4); return u;
}
__device__ __forceinline__ unsigned short bfbits(float v) {
    return (unsigned short)(pk(v, v) & 0xffffu);
}

__global__ void prep_kernel(
    const float* __restrict__ W1, const float* __restrict__ b1,
    const float* __restrict__ W2, const float* __restrict__ b2,
    const float* __restrict__ W3, const float* __restrict__ b3,
    const float* __restrict__ Wm, const float* __restrict__ bm,
    const float* __restrict__ Wv, const float* __restrict__ bv,
    const float* __restrict__ Wd1, const float* __restrict__ bd1,
    const float* __restrict__ Wd2, const float* __restrict__ bd2,
    unsigned char* __restrict__ ws)
{
    const int g0 = blockIdx.x * TPB + threadIdx.x;
    const int gs = gridDim.x * TPB;
    // W2 as A-fragments of s^T = W2 . x1^T, permuted K
    unsigned short* w2f = (unsigned short*)(ws + G_W2F);
    for (int i = g0; i < 6144; i += gs) {
        int j = i & 7, lane = (i >> 3) & 63, ts = i >> 9;
        int t = ts >> 2, s = ts & 3, q = lane >> 4;
        int n = 16 * t + (lane & 15);
        int phys = 16 * (2 * s + (j >> 2)) + 4 * q + (j & 3);   // 0..127
        w2f[i] = (n < 39) ? f2bf(W2[n * 128 + phys]) : 0;
    }
    // W3 as A-fragments of x3^T = W3 . s^T, permuted K (39 padded to 64)
    unsigned short* w3f = (unsigned short*)(ws + G_W3F);
    for (int i = g0; i < 8192; i += gs) {
        int j = i & 7, lane = (i >> 3) & 63, ns = i >> 9;
        int nt = ns >> 1, s = ns & 1, q = lane >> 4;
        int n = 16 * nt + (lane & 15);
        int phys = 16 * (2 * s + (j >> 2)) + 4 * q + (j & 3);   // 0..63
        w3f[i] = (phys < 39) ? f2bf(W3[n * 39 + phys]) : 0;
    }
    // Wm|Wv as A-fragments, permuted K=128
    unsigned short* mvf = (unsigned short*)(ws + G_MVF);
    for (int i = g0; i < 2048; i += gs) {
        int j = i & 7, lane = (i >> 3) & 63, s = i >> 9;
        int q = lane >> 4, n = lane & 15;
        int phys = 16 * (2 * s + (j >> 2)) + 4 * q + (j & 3);
        mvf[i] = f2bf(n < 8 ? Wm[n * 128 + phys] : Wv[(n - 8) * 128 + phys]);
    }
    // Wd1 as A-fragments, per-quad feature map (see header comment)
    unsigned short* d1f = (unsigned short*)(ws + G_D1F);
    for (int i = g0; i < 1024; i += gs) {
        int j = i & 7, lane = (i >> 3) & 63, tt = i >> 9;
        int q = lane >> 4, n = 16 * tt + (lane & 15);
        float v = 0.f;
        if (q == 0)      v = Wd1[n * 25 + 5 + j];            // icO[0..7]
        else if (j < 4)  v = Wd1[n * 25 + 13 + 4 * (q - 1) + j];
        // q1 j0..3 -> cols 13..16 (icO[8..11]); q2 -> 17..20 (z0..3);
        // q3 -> 21..24 (z4..7); all j>=4 (q>0) zero.
        d1f[i] = (q == 0 || j < 4) ? f2bf(v) : 0;
    }
    // Wd2 as A-fragments, permuted K=32
    unsigned short* d2f = (unsigned short*)(ws + G_D2F);
    for (int i = g0; i < 512; i += gs) {
        int j = i & 7, lane = i >> 3;
        int q = lane >> 4, n = lane & 15;
        int phys = 16 * (j >> 2) + 4 * q + (j & 3);
        d2f[i] = (n < 12) ? f2bf(Wd2[n * 32 + phys]) : 0;
    }
    // L1 coefficient image: [e][lane][mt] ushort (one ds_read_b128 per lane):
    //   quad q j0 slot carries: q0 -> a0 = W1[n][10], q1 -> a1 = W1[n][11],
    //   q2 -> a2 = W1[n][12], q3 -> ce = W1[n][0] + W1[n][6+e] + b1[n],
    //   with n = 16*mt + n16.
    unsigned short* ceab = (unsigned short*)(ws + G_CEAB);
    for (int i = g0; i < 2048; i += gs) {
        int mt = i & 7, lane = (i >> 3) & 63, e = i >> 9;
        int q = lane >> 4, n = 16 * mt + (lane & 15);
        float v = (q == 0) ? W1[n * 13 + 10]
                : (q == 1) ? W1[n * 13 + 11]
                : (q == 2) ? W1[n * 13 + 12]
                           : (W1[n * 13 + 0] + W1[n * 13 + 6 + e] + b1[n]);
        ceab[i] = f2bf(v);
    }
    float* fb = (float*)(ws + G_B2P);
    for (int i = g0; i < 48; i += gs) fb[i] = (i < 39) ? b2[i] : 0.f;
    fb = (float*)(ws + G_B3);
    for (int i = g0; i < 128; i += gs) fb[i] = b3[i];
    fb = (float*)(ws + G_BMV);
    for (int i = g0; i < 16; i += gs) fb[i] = (i < 8) ? bm[i] : bv[i - 8];
    fb = (float*)(ws + G_D1C);
    for (int i = g0; i < 32; i += gs) fb[i] = Wd1[i * 25 + 0] + bd1[i];
    fb = (float*)(ws + G_BD2);
    for (int i = g0; i < 16; i += gs) fb[i] = (i < 12) ? bd2[i] : 0.f;
}

union S8 { short8 v; uint4 u; };

#define MFMA(a, b, c) __builtin_amdgcn_mfma_f32_16x16x32_bf16(a, b, c, 0, 0, 0)

// r10 structure exactly (TPB=256, 59.8us best) + ONLY the CEAB b128 relayout
// from r11 (unbundled: r11's TPB=512 half caused the 65.5us regression via
// coarser residency granularity — occupancy 27->21%).
// L1 coeffs: 1 ds_read_b128 per edge (was 8 ds_read_u16); extraction is one
// compile-time-indexed mask/shift per mt.
__global__ __launch_bounds__(TPB, 2) void vae_mfma(
    const float* __restrict__ ic, const float* __restrict__ cc,
    const float* __restrict__ eps,
    const unsigned char* __restrict__ ws,
    float* __restrict__ out, int B)
{
    __shared__ __attribute__((aligned(16))) unsigned char lds[G_END];
    const int tid = threadIdx.x;

    {   // weight image -> LDS (linear, coalesced; L2-hot)
        const uint4* src = (const uint4*)ws;
        uint4* dst = (uint4*)lds;
        #pragma unroll
        for (int it = 0; it < 10; it++) {
            int idx = it * TPB + tid;
            if (idx < G_END / 16) dst[idx] = src[idx];
        }
    }
    __syncthreads();

    const int lane = tid & 63, w = tid >> 6;
    const int quad = lane >> 4, n16 = lane & 15;
    const long rb = ((long)blockIdx.x * 4 + w) * 16;
    const long Rl = rb + n16;              // this lane's batch row

    // ---- per-quad predicate values (k=4q slot), packed bf16 low-half ----
    unsigned int bpv[4];
    {
        const float* crow = cc + Rl * 30;
        float pv0, pv1, pv2, pv3;
        if (quad == 0) {                    // pa: cols 0..3
            float2 t0 = *(const float2*)(crow);
            float2 t1 = *(const float2*)(crow + 2);
            pv0 = t0.x; pv1 = t0.y; pv2 = t1.x; pv3 = t1.y;
        } else if (quad == 1) {             // pb: cols 10..13
            float2 t0 = *(const float2*)(crow + 10);
            float2 t1 = *(const float2*)(crow + 12);
            pv0 = t0.x; pv1 = t0.y; pv2 = t1.x; pv3 = t1.y;
        } else if (quad == 2) {             // pc: cols 14,18,22,26
            pv0 = crow[14]; pv1 = crow[18]; pv2 = crow[22]; pv3 = crow[26];
        } else {                            // bias lane: 1.0
            pv0 = pv1 = pv2 = pv3 = 1.0f;
        }
        bpv[0] = (unsigned int)bfbits(pv0);
        bpv[1] = (unsigned int)bfbits(pv1);
        bpv[2] = (unsigned int)bfbits(pv2);
        bpv[3] = (unsigned int)bfbits(pv3);
    }

    // ---- W2 A-frags resident (from LDS) + per-quad bias vectors ----
    S8 W2F[12];
    #pragma unroll
    for (int ts = 0; ts < 12; ts++)
        W2F[ts].u = *(const uint4*)(lds + G_W2F + (ts * 64 + lane) * 16);
    const float* b2p = (const float*)(lds + G_B2P);
    f32x4 b2q[3];
    #pragma unroll
    for (int t = 0; t < 3; t++)
        b2q[t] = *(const f32x4*)(b2p + 16 * t + 4 * quad);

    f32x4 ss0 = {0,0,0,0}, ss1 = {0,0,0,0}, ss2 = {0,0,0,0};

    // ---- message MLP: L1 (x1^T tiles) -> in-reg pack -> L2 (s^T) ----
    #pragma unroll
    for (int e = 0; e < 4; e++) {
        S8 bp;                              // B: k=4q slot = this quad's p-value
        bp.u.x = bpv[e]; bp.u.y = 0u; bp.u.z = 0u; bp.u.w = 0u;
        S8 ce8;                             // this lane's 8 mt-coeffs, 1 b128
        ce8.u = *(const uint4*)(lds + G_CEAB + e * 1024 + lane * 16);
        S8 xf[4];                           // x1^T B-frags for L2 (perm K)
        #pragma unroll
        for (int mt = 0; mt < 8; mt++) {
            unsigned int cws[4] = {ce8.u.x, ce8.u.y, ce8.u.z, ce8.u.w};
            unsigned int cw = cws[mt >> 1];           // compile-time index
            S8 af;                          // A: k=4q slot = coeff type q
            af.u.x = (mt & 1) ? (cw >> 16) : (cw & 0xffffu);
            af.u.y = 0u; af.u.z = 0u; af.u.w = 0u;
            f32x4 z4 = {0,0,0,0};
            f32x4 cr = MFMA(af.v, bp.v, z4);   // lane: x1[b=n16][16mt+4q+r]
            unsigned int lo = pk(fmaxf(cr[0], 0.f), fmaxf(cr[1], 0.f));
            unsigned int hi = pk(fmaxf(cr[2], 0.f), fmaxf(cr[3], 0.f));
            if ((mt & 1) == 0) { xf[mt >> 1].u.x = lo; xf[mt >> 1].u.y = hi; }
            else               { xf[mt >> 1].u.z = lo; xf[mt >> 1].u.w = hi; }
        }
        f32x4 c0 = b2q[0], c1 = b2q[1], c2 = b2q[2];
        #pragma unroll
        for (int s = 0; s < 4; s++) {
            c0 = MFMA(W2F[s].v,     xf[s].v, c0);
            c1 = MFMA(W2F[4 + s].v, xf[s].v, c1);
            c2 = MFMA(W2F[8 + s].v, xf[s].v, c2);
        }
        #pragma unroll
        for (int r = 0; r < 4; r++) {
            ss0[r] += fmaxf(c0[r], 0.f);
            ss1[r] += fmaxf(c1[r], 0.f);
            ss2[r] += fmaxf(c2[r], 0.f);
        }
    }

    // ---- s^T B-frags (K=64, tiles 3 valid + 1 zero pad) ----
    S8 sf0, sf1;
    sf0.u.x = pk(ss0[0], ss0[1]); sf0.u.y = pk(ss0[2], ss0[3]);
    sf0.u.z = pk(ss1[0], ss1[1]); sf0.u.w = pk(ss1[2], ss1[3]);
    sf1.u.x = pk(ss2[0], ss2[1]); sf1.u.y = pk(ss2[2], ss2[3]);
    sf1.u.z = 0u; sf1.u.w = 0u;   // rows 48..63 pad (rows 39..47 exact zero)

    // ---- L3: x3^T = W3 . s^T ; pack heads B-frags on the fly ----
    const uint4* w3l = (const uint4*)(lds + G_W3F);
    const float* b3p = (const float*)(lds + G_B3);
    S8 hf[4];
    #pragma unroll
    for (int nt = 0; nt < 8; nt++) {
        f32x4 c = *(const f32x4*)(b3p + nt * 16 + 4 * quad);
        S8 a0, a1;
        a0.u = w3l[(nt * 2 + 0) * 64 + lane];
        a1.u = w3l[(nt * 2 + 1) * 64 + lane];
        c = MFMA(a0.v, sf0.v, c);
        c = MFMA(a1.v, sf1.v, c);
        unsigned int lo = pk(fmaxf(c[0], 0.f), fmaxf(c[1], 0.f));
        unsigned int hi = pk(fmaxf(c[2], 0.f), fmaxf(c[3], 0.f));
        if ((nt & 1) == 0) { hf[nt >> 1].u.x = lo; hf[nt >> 1].u.y = hi; }
        else               { hf[nt >> 1].u.z = lo; hf[nt >> 1].u.w = hi; }
    }

    // ---- heads: cm = [mn|lv]^T rows 4q+r; cm2 = same weights half-rotated
    //      (rows (4q+r+8)&15) so each lane owns its (mn,lv) pair ----
    f32x4 cm  = *(const f32x4*)((const float*)(lds + G_BMV) + 4 * quad);
    f32x4 cm2 = *(const f32x4*)((const float*)(lds + G_BMV) + 4 * ((quad + 2) & 3));
    const int laneSw = quad * 16 + ((n16 + 8) & 15);
    #pragma unroll
    for (int s = 0; s < 4; s++) {
        S8 a, a2;
        a.u  = *(const uint4*)(lds + G_MVF + (s * 64 + lane) * 16);
        a2.u = *(const uint4*)(lds + G_MVF + (s * 64 + laneSw) * 16);
        cm  = MFMA(a.v,  hf[s].v, cm);
        cm2 = MFMA(a2.v, hf[s].v, cm2);
    }

    // ---- reparameterization, fully lane-local ----
    float4 ev = *(const float4*)(eps + Rl * 8 + 4 * (quad & 1));
    f32x4 zz;
    {
        const bool lo2 = (quad < 2);
        float mn0 = lo2 ? cm[0] : cm2[0], lv0 = lo2 ? cm2[0] : cm[0];
        float mn1 = lo2 ? cm[1] : cm2[1], lv1 = lo2 ? cm2[1] : cm[1];
        float mn2 = lo2 ? cm[2] : cm2[2], lv2 = lo2 ? cm2[2] : cm[2];
        float mn3 = lo2 ? cm[3] : cm2[3], lv3 = lo2 ? cm2[3] : cm[3];
        zz[0] = fmaf(ev.x, __expf(0.5f * lv0), mn0);
        zz[1] = fmaf(ev.y, __expf(0.5f * lv1), mn1);
        zz[2] = fmaf(ev.z, __expf(0.5f * lv2), mn2);
        zz[3] = fmaf(ev.w, __expf(0.5f * lv3), mn3);
    }
    // stores: q0/q1 -> means (cm = mn rows), q2/q3 -> logvar (cm = lv rows)
    float* pml = (float*)((quad < 2) ? (out + (long)B * 12) : (out + (long)B * 20));
    *(float4*)(pml + Rl * 8 + 4 * (quad & 1)) = *(float4*)&cm;
    if (quad < 2)
        *(float4*)(out + (long)B * 28 + Rl * 8 + 4 * quad) = *(float4*)&zz;

    // ---- decoder input B-frag, per-quad feature map (no exchange) ----
    S8 df;
    if (quad == 0) {                        // icO[0..7] = ic cols 0..3,10..13
        const float* irow = ic + Rl * 30;
        float2 a0 = *(const float2*)(irow);
        float2 a1 = *(const float2*)(irow + 2);
        float2 a2 = *(const float2*)(irow + 10);
        float2 a3 = *(const float2*)(irow + 12);
        df.u.x = pk(a0.x, a0.y); df.u.y = pk(a1.x, a1.y);
        df.u.z = pk(a2.x, a2.y); df.u.w = pk(a3.x, a3.y);
    } else if (quad == 1) {                 // icO[8..11] = ic cols 14,18,22,26
        const float* irow = ic + Rl * 30;
        df.u.x = pk(irow[14], irow[18]);
        df.u.y = pk(irow[22], irow[26]);
        df.u.z = 0u; df.u.w = 0u;
    } else {                                // q2: z[0..3], q3: z[4..7] (local)
        df.u.x = pk(zz[0], zz[1]);
        df.u.y = pk(zz[2], zz[3]);
        df.u.z = 0u; df.u.w = 0u;
    }

    // ---- decoder layer 1: h^T (2 tiles) ----
    const float* d1c = (const float*)(lds + G_D1C);
    S8 a;
    f32x4 ct = *(const f32x4*)(d1c + 4 * quad);
    a.u = *(const uint4*)(lds + G_D1F + (0 * 64 + lane) * 16);
    f32x4 h0 = MFMA(a.v, df.v, ct);
    ct = *(const f32x4*)(d1c + 16 + 4 * quad);
    a.u = *(const uint4*)(lds + G_D1F + (1 * 64 + lane) * 16);
    f32x4 h1 = MFMA(a.v, df.v, ct);
    S8 hf2;
    hf2.u.x = pk(fmaxf(h0[0], 0.f), fmaxf(h0[1], 0.f));
    hf2.u.y = pk(fmaxf(h0[2], 0.f), fmaxf(h0[3], 0.f));
    hf2.u.z = pk(fmaxf(h1[0], 0.f), fmaxf(h1[1], 0.f));
    hf2.u.w = pk(fmaxf(h1[2], 0.f), fmaxf(h1[3], 0.f));

    // ---- decoder layer 2 + sigmoid + coalesced float4 recon store ----
    f32x4 c2 = *(const f32x4*)((const float*)(lds + G_BD2) + 4 * quad);
    S8 a2; a2.u = *(const uint4*)(lds + G_D2F + lane * 16);
    c2 = MFMA(a2.v, hf2.v, c2);
    if (quad < 3) {
        float4 o;
        o.x = 1.f / (1.f + __expf(-c2[0]));
        o.y = 1.f / (1.f + __expf(-c2[1]));
        o.z = 1.f / (1.f + __expf(-c2[2]));
        o.w = 1.f / (1.f + __expf(-c2[3]));
        *(float4*)(out + Rl * 12 + 4 * quad) = o;
    }
}

extern "C" void kernel_launch(void* const* d_in, const int* in_sizes, int n_in,
                              void* d_out, int out_size, void* d_ws, size_t ws_size,
                              hipStream_t stream) {
    const float* ic  = (const float*)d_in[0];   // initial_c [B,30]
    const float* cc  = (const float*)d_in[2];   // current_c [B,30]
    const float* eps = (const float*)d_in[3];   // eps [B,8]

    const int B = in_sizes[3] / 8;              // 262144
    const int nblocks = B / 64;                 // 4096

    prep_kernel<<<PREP_BLOCKS, TPB, 0, stream>>>(
        (const float*)d_in[4],  (const float*)d_in[5],
        (const float*)d_in[6],  (const float*)d_in[7],
        (const float*)d_in[8],  (const float*)d_in[9],
        (const float*)d_in[10], (const float*)d_in[11],
        (const float*)d_in[12], (const float*)d_in[13],
        (const float*)d_in[14], (const float*)d_in[15],
        (const float*)d_in[16], (const float*)d_in[17],
        (unsigned char*)d_ws);
    vae_mfma<<<nblocks, TPB, 0, stream>>>(
        ic, cc, eps, (const unsigned char*)d_ws, (float*)d_out, B);
}